// Round 5
// baseline (17.619 us; speedup 1.0000x reference)
//
#include <hip/hip_runtime.h>

#define BATCH 16384
#define FDIM 256
#define ROWS_PER_WAVE 8
#define WAVES_PER_BLOCK 8                                    // 512 threads/block
#define NBLOCKS (BATCH / (ROWS_PER_WAVE * WAVES_PER_BLOCK))  // 256 blocks

__global__ __launch_bounds__(512) void center_loss_fused(
    const float* __restrict__ feat,
    const int* __restrict__ labels,
    const float* __restrict__ centers,
    float* __restrict__ out)
{
    const int wave = threadIdx.x >> 6;
    const int lane = threadIdx.x & 63;
    // 8 consecutive rows per wave; row base is wave-uniform.
    int row0 = (blockIdx.x * WAVES_PER_BLOCK + wave) * ROWS_PER_WAVE;
    // Uniform -> labels load becomes one s_load_dwordx8.
    row0 = __builtin_amdgcn_readfirstlane(row0);

    int lab[ROWS_PER_WAVE];
    #pragma unroll
    for (int r = 0; r < ROWS_PER_WAVE; ++r)
        lab[r] = labels[row0 + r];

    const float4* feat4 = reinterpret_cast<const float4*>(feat);
    const float4* cent4 = reinterpret_cast<const float4*>(centers);

    // 16 independent 16B loads per lane (8 feat + 8 center).
    float4 fv[ROWS_PER_WAVE], cv[ROWS_PER_WAVE];
    #pragma unroll
    for (int r = 0; r < ROWS_PER_WAVE; ++r)
        fv[r] = feat4[(size_t)(row0 + r) * 64 + lane];
    #pragma unroll
    for (int r = 0; r < ROWS_PER_WAVE; ++r)
        cv[r] = cent4[(size_t)lab[r] * 64 + lane];

    float s = 0.0f;
    #pragma unroll
    for (int r = 0; r < ROWS_PER_WAVE; ++r) {
        float dx = fv[r].x - cv[r].x;
        float dy = fv[r].y - cv[r].y;
        float dz = fv[r].z - cv[r].z;
        float dw = fv[r].w - cv[r].w;
        s += dx * dx + dy * dy + dz * dz + dw * dw;
    }

    // Wave-level reduction across 64 lanes.
    #pragma unroll
    for (int off = 32; off > 0; off >>= 1)
        s += __shfl_down(s, off, 64);

    __shared__ float wsum[WAVES_PER_BLOCK];
    if (lane == 0) wsum[wave] = s;
    __syncthreads();

    if (threadIdx.x == 0) {
        float t = 0.0f;
        #pragma unroll
        for (int i = 0; i < WAVES_PER_BLOCK; ++i) t += wsum[i];
        // 256 same-address atomics @ ~14ns RMW each = ~3.6us of TCC capacity,
        // spread across ~6us of kernel execution -> hidden.
        atomicAdd(out, t * (1.0f / (2.0f * BATCH)));
    }
}

extern "C" void kernel_launch(void* const* d_in, const int* in_sizes, int n_in,
                              void* d_out, int out_size, void* d_ws, size_t ws_size,
                              hipStream_t stream) {
    const float* feat    = (const float*)d_in[0];
    const int*   labels  = (const int*)d_in[1];
    const float* centers = (const float*)d_in[2];
    float* out = (float*)d_out;

    // Atomics accumulate; harness never re-poisons d_out between replays.
    hipMemsetAsync(out, 0, sizeof(float), stream);
    center_loss_fused<<<NBLOCKS, 512, 0, stream>>>(feat, labels, centers, out);
}

// Round 6
// 11.238 us; speedup vs baseline: 1.5677x; 1.5677x over previous
//
#include <hip/hip_runtime.h>

#define BATCH 16384
#define FDIM 256
#define ROWS_PER_WAVE 8
#define NBLOCKS (BATCH / ROWS_PER_WAVE)  // 2048 single-wave blocks

// One wave per block: no LDS, no __syncthreads, each wave retires as soon as
// its own loads land (no straggler coupling across waves in a block).
__global__ __launch_bounds__(64) void center_loss_partial(
    const float* __restrict__ feat,
    const int* __restrict__ labels,
    const float* __restrict__ centers,
    float* __restrict__ partials)
{
    const int lane = threadIdx.x;            // 0..63
    const int row0 = blockIdx.x * ROWS_PER_WAVE;  // SGPR-uniform

    // Wave-uniform -> one scalar s_load burst for all 8 labels.
    int lab[ROWS_PER_WAVE];
    #pragma unroll
    for (int r = 0; r < ROWS_PER_WAVE; ++r)
        lab[r] = labels[row0 + r];

    const float4* feat4 = reinterpret_cast<const float4*>(feat);
    const float4* cent4 = reinterpret_cast<const float4*>(centers);

    // 16 independent 16B loads per lane (8 feat + 8 center).
    float4 fv[ROWS_PER_WAVE], cv[ROWS_PER_WAVE];
    #pragma unroll
    for (int r = 0; r < ROWS_PER_WAVE; ++r)
        fv[r] = feat4[(size_t)(row0 + r) * 64 + lane];
    #pragma unroll
    for (int r = 0; r < ROWS_PER_WAVE; ++r)
        cv[r] = cent4[(size_t)lab[r] * 64 + lane];

    float s = 0.0f;
    #pragma unroll
    for (int r = 0; r < ROWS_PER_WAVE; ++r) {
        float dx = fv[r].x - cv[r].x;
        float dy = fv[r].y - cv[r].y;
        float dz = fv[r].z - cv[r].z;
        float dw = fv[r].w - cv[r].w;
        s += dx * dx + dy * dy + dz * dz + dw * dw;
    }

    // Wave-level reduction across 64 lanes.
    #pragma unroll
    for (int off = 32; off > 0; off >>= 1)
        s += __shfl_down(s, off, 64);

    if (lane == 0)
        partials[blockIdx.x] = s;
}

// Single-wave final reduce: 2048 partials = 64 lanes x 8 float4,
// all 8 loads issued independently (one latency round).
__global__ __launch_bounds__(64) void center_loss_final(
    const float* __restrict__ partials,
    float* __restrict__ out)
{
    const int lane = threadIdx.x;
    const float4* p4 = reinterpret_cast<const float4*>(partials);

    float4 v[8];
    #pragma unroll
    for (int i = 0; i < 8; ++i)
        v[i] = p4[i * 64 + lane];

    float s = 0.0f;
    #pragma unroll
    for (int i = 0; i < 8; ++i)
        s += ((v[i].x + v[i].y) + (v[i].z + v[i].w));

    #pragma unroll
    for (int off = 32; off > 0; off >>= 1)
        s += __shfl_down(s, off, 64);

    if (lane == 0)
        out[0] = s * (1.0f / (2.0f * BATCH));
}

extern "C" void kernel_launch(void* const* d_in, const int* in_sizes, int n_in,
                              void* d_out, int out_size, void* d_ws, size_t ws_size,
                              hipStream_t stream) {
    const float* feat    = (const float*)d_in[0];
    const int*   labels  = (const int*)d_in[1];
    const float* centers = (const float*)d_in[2];
    float* out      = (float*)d_out;
    float* partials = (float*)d_ws;  // 2048 floats, fully rewritten each call

    center_loss_partial<<<NBLOCKS, 64, 0, stream>>>(feat, labels, centers, partials);
    center_loss_final<<<1, 64, 0, stream>>>(partials, out);
}